// Round 1
// baseline (93.990 us; speedup 1.0000x reference)
//
#include <hip/hip_runtime.h>

// SpaceToDepth bs=2: x0 (16,64,256,256) f32 -> y (16,256,128,128) f32, plus x1 (16,) passthrough.
// y[b, h_in*128 + w_in*64 + c, ho, wo] = x0[b, c, 2*ho + h_in, 2*wo + w_in]
// d_out = [ y flat (67,108,864 floats) | x1 (16 floats) ]

// Compile-time shape constants (problem is fixed-shape).
constexpr int Bn = 16, Cn = 64, Hn = 256, Wn = 256;
constexpr int HOn = Hn / 2, WOn = Wn / 2;              // 128, 128
constexpr long long Y_ELEMS = (long long)Bn * (4 * Cn) * HOn * WOn;  // 67,108,864
constexpr long long N_F4 = (long long)Bn * Cn * Hn * Wn / 4;         // 16,777,216 float4 units
constexpr long long WIN1_OFF = (long long)Cn * HOn * WOn;            // 1,048,576 (d += 64)

__global__ void __launch_bounds__(256) s2d_kernel(const float4* __restrict__ in,
                                                  const float* __restrict__ x1,
                                                  float* __restrict__ out) {
    long long t = (long long)blockIdx.x * blockDim.x + threadIdx.x;  // one float4 per thread

    // input flat float4 index t decomposes as (b, c, h, w4) with W4=64, H=256, C=64
    int w4 = (int)(t & 63);          // 4*w4 = input w base
    int h  = (int)((t >> 6) & 255);
    int c  = (int)((t >> 14) & 63);
    int b  = (int)(t >> 20);

    float4 v = in[t];                // fully coalesced 16B/lane

    int ho  = h >> 1;
    int hin = h & 1;
    int wo  = w4 << 1;               // even -> float2 stores are 8B-aligned

    // w_in = 0 channel: d = hin*128 + c ; w_in = 1 channel: d += 64
    long long base = ((((long long)b * 256 + (long long)(hin * 128 + c)) * HOn) + ho) * WOn + wo;

    *reinterpret_cast<float2*>(out + base)            = make_float2(v.x, v.z);
    *reinterpret_cast<float2*>(out + base + WIN1_OFF) = make_float2(v.y, v.w);

    // x1 passthrough (16 floats) appended after y
    if (blockIdx.x == 0 && threadIdx.x < 16) {
        out[Y_ELEMS + threadIdx.x] = x1[threadIdx.x];
    }
}

extern "C" void kernel_launch(void* const* d_in, const int* in_sizes, int n_in,
                              void* d_out, int out_size, void* d_ws, size_t ws_size,
                              hipStream_t stream) {
    const float4* x0 = (const float4*)d_in[0];
    const float*  x1 = (const float*)d_in[1];
    float* out = (float*)d_out;

    const int block = 256;
    const long long grid = N_F4 / block;  // 65,536 blocks, exact
    s2d_kernel<<<(int)grid, block, 0, stream>>>(x0, x1, out);
}